// Round 3
// baseline (911.512 us; speedup 1.0000x reference)
//
#include <hip/hip_runtime.h>
#include <hip/hip_bf16.h>

#define T_TOK 4096
#define H_DIM 2048
#define F_DIM 1280
#define NE 12

typedef float f32x4 __attribute__((ext_vector_type(4)));
typedef short bf16x8 __attribute__((ext_vector_type(8)));

__device__ __forceinline__ unsigned short f2bf(float f) {
    unsigned int u = __float_as_uint(f);
    u += 0x7FFFu + ((u >> 16) & 1u);   // RNE
    return (unsigned short)(u >> 16);
}

// packed f32x2 -> bf16x2 (v_cvt_pk_bf16_f32 on gfx950 via HIP API)
__device__ __forceinline__ unsigned int f2bf2(float lo, float hi) {
    __hip_bfloat162 p = __float22bfloat162_rn(make_float2(lo, hi));
    return *(unsigned int*)&p;
}

// async global->LDS, 16B per lane. LDS dest = wave-uniform base + lane*16.
__device__ __forceinline__ void gl2lds16(const void* g, void* l) {
    __builtin_amdgcn_global_load_lds(
        (const __attribute__((address_space(1))) unsigned int*)g,
        (__attribute__((address_space(3))) unsigned int*)l,
        16, 0, 0);
}

// ---------------- fp32 -> bf16 streaming convert (x only) ----------------
__global__ __launch_bounds__(256) void convert_kernel(
    const float* __restrict__ src, unsigned short* __restrict__ dst)
{
    size_t i = ((size_t)blockIdx.x * 256 + threadIdx.x) * 8;
    float4 a = *(const float4*)(src + i);
    float4 b = *(const float4*)(src + i + 4);
    unsigned int o[4];
    o[0] = f2bf2(a.x, a.y); o[1] = f2bf2(a.z, a.w);
    o[2] = f2bf2(b.x, b.y); o[3] = f2bf2(b.z, b.w);
    *(uint4*)(dst + i) = *(const uint4*)o;
}

// ---------------- gating ----------------
__global__ __launch_bounds__(256) void gate_kernel(
    const float* __restrict__ x, const float* __restrict__ gw,
    int* __restrict__ counts, int* __restrict__ top_e, float* __restrict__ top_w)
{
    int gid = blockIdx.x * blockDim.x + threadIdx.x;
    int tok = gid >> 6;
    int lane = threadIdx.x & 63;
    if (tok >= T_TOK) return;
    const float* xr = x + (size_t)tok * H_DIM;
    float4 xs[8];
#pragma unroll
    for (int c = 0; c < 8; ++c) xs[c] = *(const float4*)(xr + c * 256 + lane * 4);
    float acc[NE];
#pragma unroll
    for (int e = 0; e < NE; ++e) {
        const float* gr = gw + (size_t)e * H_DIM;
        float s = 0.f;
#pragma unroll
        for (int c = 0; c < 8; ++c) {
            float4 g = *(const float4*)(gr + c * 256 + lane * 4);
            s += xs[c].x * g.x + xs[c].y * g.y + xs[c].z * g.z + xs[c].w * g.w;
        }
        acc[e] = s;
    }
#pragma unroll
    for (int e = 0; e < NE; ++e) {
#pragma unroll
        for (int off = 32; off > 0; off >>= 1)
            acc[e] += __shfl_xor(acc[e], off, 64);
    }
    if (lane == 0) {
        int b0 = 0;
#pragma unroll
        for (int e = 1; e < NE; ++e) if (acc[e] > acc[b0]) b0 = e;
        int b1 = (b0 == 0) ? 1 : 0;
#pragma unroll
        for (int e = 0; e < NE; ++e) if (e != b0 && acc[e] > acc[b1]) b1 = e;
        float t = __expf(acc[b1] - acc[b0]);   // <= 1
        float w0 = 1.f / (1.f + t);
        top_e[tok * 2] = b0; top_e[tok * 2 + 1] = b1;
        top_w[tok * 2] = w0; top_w[tok * 2 + 1] = 1.f - w0;
        atomicAdd(&counts[b0], 1);
        atomicAdd(&counts[b1], 1);
    }
}

__global__ void scan_kernel(const int* __restrict__ counts, int* __restrict__ offsets,
                            int* __restrict__ cursors)
{
    if (threadIdx.x == 0 && blockIdx.x == 0) {
        int s = 0;
        for (int e = 0; e < NE; ++e) { offsets[e] = s; s += counts[e]; cursors[e] = 0; }
        offsets[NE] = s;
    }
}

__global__ __launch_bounds__(256) void scatter_kernel(
    const int* __restrict__ top_e, const float* __restrict__ top_w,
    const int* __restrict__ offsets, int* __restrict__ cursors,
    int* __restrict__ row_token, float* __restrict__ row_weight,
    int* __restrict__ inv_pos)
{
    int t = blockIdx.x * blockDim.x + threadIdx.x;
    if (t >= T_TOK) return;
#pragma unroll
    for (int s = 0; s < 2; ++s) {
        int e = top_e[t * 2 + s];
        int pos = atomicAdd(&cursors[e], 1);
        int r = offsets[e] + pos;
        row_token[r] = t;
        row_weight[r] = top_w[t * 2 + s];
        inv_pos[t * 2 + s] = r;
    }
}

// ---------------- FFN1: block 128m x 64n (dual B), BK=64, fp32 B on the fly ----------------
// grid (64, 20, 12): x = xcd(8) * mslot(8); all m-tiles of an (e,n) strip pin to one XCD.
__global__ __launch_bounds__(256, 3) void ffn1_kernel(
    const unsigned short* __restrict__ xb, const float* __restrict__ w1,
    const float* __restrict__ w3,
    const int* __restrict__ counts, const int* __restrict__ offsets,
    const int* __restrict__ row_token, unsigned short* __restrict__ hbuf)
{
    int e = blockIdx.z;
    int n_blk = blockIdx.y;
    if (((blockIdx.x ^ (e * 20 + n_blk)) & 7) != 0) return;   // XCD filter
    int m_slot = blockIdx.x >> 3;                              // 0..7
    int cnt = counts[e];
    if (m_slot * 128 >= cnt) return;
    int base = offsets[e];
    int n0 = n_blk * 64;

    __shared__ unsigned short As[128 * 64];   // 128 m-rows x 64 k (bf16, xor-swizzled chunks)
    __shared__ unsigned short Bs[128 * 64];   // rows 0-63: w1 cols, 64-127: w3 cols

    int t = threadIdx.x;
    int lane = t & 63;
    int wid = t >> 6;
    int wm = wid >> 1, wn = wid & 1;
    int lr = lane & 15, lq = lane >> 4;

    // B staging: thread -> row t>>1, logical chunks (t&1)*4 .. +3 (8 bf16 each)
    int brow = t >> 1;
    int bc0 = (t & 1) * 4;
    const float* bRowPtr = (brow < 64)
        ? (w1 + ((size_t)e * F_DIM + n0 + brow) * H_DIM + bc0 * 8)
        : (w3 + ((size_t)e * F_DIM + (n0 + brow - 64)) * H_DIM + bc0 * 8);
    unsigned short* bWr[4];
#pragma unroll
    for (int j = 0; j < 4; ++j)
        bWr[j] = Bs + brow * 64 + ((bc0 + j) ^ (brow & 7)) * 8;

    // A staging: issue i covers row i*32 + (t>>3), phys chunk t&7
    const int aoff = (((t & 7) ^ ((t >> 3) & 7))) * 8;   // logical k-chunk * 8
    unsigned short* aDst[4];
#pragma unroll
    for (int i = 0; i < 4; ++i) aDst[i] = As + i * 2048 + wid * 512 + lane * 8;

    // fragment phys chunk offsets (row&7 == lr&7 for all frag rows)
    const int po0 = ((0 + lq) ^ (lr & 7)) * 8;
    const int po1 = ((4 + lq) ^ (lr & 7)) * 8;

    for (int m0 = m_slot * 128; m0 < cnt; m0 += 1024) {
        const unsigned short* aPtr[4];
#pragma unroll
        for (int i = 0; i < 4; ++i) {
            int r = i * 32 + (t >> 3);
            int tok = row_token[base + min(m0 + r, cnt - 1)];
            aPtr[i] = xb + (size_t)tok * H_DIM + aoff;
        }
        f32x4 acc1[4][2] = {};
        f32x4 acc3[4][2] = {};

        for (int k0 = 0; k0 < H_DIM; k0 += 64) {
#pragma unroll
            for (int i = 0; i < 4; ++i) gl2lds16(aPtr[i] + k0, aDst[i]);
            // B: 32 fp32 -> 4 bf16x8 chunks, two halves to cap register pressure
#pragma unroll
            for (int h = 0; h < 2; ++h) {
                float4 v0 = *(const float4*)(bRowPtr + k0 + h * 16);
                float4 v1 = *(const float4*)(bRowPtr + k0 + h * 16 + 4);
                float4 v2 = *(const float4*)(bRowPtr + k0 + h * 16 + 8);
                float4 v3 = *(const float4*)(bRowPtr + k0 + h * 16 + 12);
                unsigned int o0[4], o1[4];
                o0[0] = f2bf2(v0.x, v0.y); o0[1] = f2bf2(v0.z, v0.w);
                o0[2] = f2bf2(v1.x, v1.y); o0[3] = f2bf2(v1.z, v1.w);
                o1[0] = f2bf2(v2.x, v2.y); o1[1] = f2bf2(v2.z, v2.w);
                o1[2] = f2bf2(v3.x, v3.y); o1[3] = f2bf2(v3.z, v3.w);
                *(uint4*)bWr[2 * h]     = *(const uint4*)o0;
                *(uint4*)bWr[2 * h + 1] = *(const uint4*)o1;
            }
            __syncthreads();
#pragma unroll
            for (int s = 0; s < 2; ++s) {
                int po = s ? po1 : po0;
                bf16x8 af[4], b1f[2], b3f[2];
#pragma unroll
                for (int ms = 0; ms < 4; ++ms)
                    af[ms] = *(const bf16x8*)(As + (wm * 64 + ms * 16 + lr) * 64 + po);
#pragma unroll
                for (int ns = 0; ns < 2; ++ns) {
                    b1f[ns] = *(const bf16x8*)(Bs + (wn * 32 + ns * 16 + lr) * 64 + po);
                    b3f[ns] = *(const bf16x8*)(Bs + (64 + wn * 32 + ns * 16 + lr) * 64 + po);
                }
#pragma unroll
                for (int ms = 0; ms < 4; ++ms)
#pragma unroll
                    for (int ns = 0; ns < 2; ++ns) {
                        acc1[ms][ns] = __builtin_amdgcn_mfma_f32_16x16x32_bf16(af[ms], b1f[ns], acc1[ms][ns], 0, 0, 0);
                        acc3[ms][ns] = __builtin_amdgcn_mfma_f32_16x16x32_bf16(af[ms], b3f[ns], acc3[ms][ns], 0, 0, 0);
                    }
            }
            __syncthreads();
        }

#pragma unroll
        for (int ms = 0; ms < 4; ++ms) {
#pragma unroll
            for (int i = 0; i < 4; ++i) {
                int r = wm * 64 + ms * 16 + lq * 4 + i;
                if (m0 + r < cnt) {
                    size_t rowoff = (size_t)(base + m0 + r) * F_DIM;
#pragma unroll
                    for (int ns = 0; ns < 2; ++ns) {
                        int c = n0 + wn * 32 + ns * 16 + lr;
                        float a = acc1[ms][ns][i];
                        float hv = (a / (1.f + __expf(-a))) * acc3[ms][ns][i];
                        hbuf[rowoff + c] = f2bf(hv);
                    }
                }
            }
        }
    }
}

// ---------------- FFN2: block 128m x 128n, BK=64, fp32 w2 on the fly ----------------
// grid (64, 16, 12)
__global__ __launch_bounds__(256, 3) void ffn2_kernel(
    const unsigned short* __restrict__ hbuf, const float* __restrict__ w2,
    const int* __restrict__ counts, const int* __restrict__ offsets,
    const float* __restrict__ row_weight, float* __restrict__ ybuf)
{
    int e = blockIdx.z;
    int n_blk = blockIdx.y;
    if (((blockIdx.x ^ (e * 16 + n_blk)) & 7) != 0) return;
    int m_slot = blockIdx.x >> 3;
    int cnt = counts[e];
    if (m_slot * 128 >= cnt) return;
    int base = offsets[e];
    int n0 = n_blk * 128;

    __shared__ unsigned short As[128 * 64];
    __shared__ unsigned short Bs[128 * 64];

    int t = threadIdx.x;
    int lane = t & 63;
    int wid = t >> 6;
    int wm = wid >> 1, wn = wid & 1;
    int lr = lane & 15, lq = lane >> 4;

    int brow = t >> 1;
    int bc0 = (t & 1) * 4;
    const float* bRowPtr = w2 + ((size_t)e * H_DIM + n0 + brow) * F_DIM + bc0 * 8;
    unsigned short* bWr[4];
#pragma unroll
    for (int j = 0; j < 4; ++j)
        bWr[j] = Bs + brow * 64 + ((bc0 + j) ^ (brow & 7)) * 8;

    const int aoff = (((t & 7) ^ ((t >> 3) & 7))) * 8;
    unsigned short* aDst[4];
#pragma unroll
    for (int i = 0; i < 4; ++i) aDst[i] = As + i * 2048 + wid * 512 + lane * 8;

    const int po0 = ((0 + lq) ^ (lr & 7)) * 8;
    const int po1 = ((4 + lq) ^ (lr & 7)) * 8;

    for (int m0 = m_slot * 128; m0 < cnt; m0 += 1024) {
        const unsigned short* aPtr[4];
#pragma unroll
        for (int i = 0; i < 4; ++i) {
            int r = i * 32 + (t >> 3);
            aPtr[i] = hbuf + (size_t)(base + min(m0 + r, cnt - 1)) * F_DIM + aoff;
        }
        f32x4 acc[4][4] = {};

        for (int k0 = 0; k0 < F_DIM; k0 += 64) {
#pragma unroll
            for (int i = 0; i < 4; ++i) gl2lds16(aPtr[i] + k0, aDst[i]);
#pragma unroll
            for (int h = 0; h < 2; ++h) {
                float4 v0 = *(const float4*)(bRowPtr + k0 + h * 16);
                float4 v1 = *(const float4*)(bRowPtr + k0 + h * 16 + 4);
                float4 v2 = *(const float4*)(bRowPtr + k0 + h * 16 + 8);
                float4 v3 = *(const float4*)(bRowPtr + k0 + h * 16 + 12);
                unsigned int o0[4], o1[4];
                o0[0] = f2bf2(v0.x, v0.y); o0[1] = f2bf2(v0.z, v0.w);
                o0[2] = f2bf2(v1.x, v1.y); o0[3] = f2bf2(v1.z, v1.w);
                o1[0] = f2bf2(v2.x, v2.y); o1[1] = f2bf2(v2.z, v2.w);
                o1[2] = f2bf2(v3.x, v3.y); o1[3] = f2bf2(v3.z, v3.w);
                *(uint4*)bWr[2 * h]     = *(const uint4*)o0;
                *(uint4*)bWr[2 * h + 1] = *(const uint4*)o1;
            }
            __syncthreads();
#pragma unroll
            for (int s = 0; s < 2; ++s) {
                int po = s ? po1 : po0;
                bf16x8 af[4], bf[4];
#pragma unroll
                for (int ms = 0; ms < 4; ++ms)
                    af[ms] = *(const bf16x8*)(As + (wm * 64 + ms * 16 + lr) * 64 + po);
#pragma unroll
                for (int ns = 0; ns < 4; ++ns)
                    bf[ns] = *(const bf16x8*)(Bs + (wn * 64 + ns * 16 + lr) * 64 + po);
#pragma unroll
                for (int ms = 0; ms < 4; ++ms)
#pragma unroll
                    for (int ns = 0; ns < 4; ++ns)
                        acc[ms][ns] = __builtin_amdgcn_mfma_f32_16x16x32_bf16(af[ms], bf[ns], acc[ms][ns], 0, 0, 0);
            }
            __syncthreads();
        }

#pragma unroll
        for (int ms = 0; ms < 4; ++ms) {
#pragma unroll
            for (int i = 0; i < 4; ++i) {
                int r = wm * 64 + ms * 16 + lq * 4 + i;
                if (m0 + r < cnt) {
                    float wgt = row_weight[base + m0 + r];
                    size_t rowoff = (size_t)(base + m0 + r) * H_DIM;
#pragma unroll
                    for (int ns = 0; ns < 4; ++ns) {
                        int c = n0 + wn * 64 + ns * 16 + lr;
                        ybuf[rowoff + c] = acc[ms][ns][i] * wgt;
                    }
                }
            }
        }
    }
}

// ---------------- combine: out[t] = ybuf[pos0] + ybuf[pos1] ----------------
__global__ __launch_bounds__(256) void combine_kernel(
    const float* __restrict__ ybuf, const int* __restrict__ inv_pos,
    float* __restrict__ out)
{
    int tk = blockIdx.x;
    int p0 = inv_pos[2 * tk];
    int p1 = inv_pos[2 * tk + 1];
    const float4* y0 = (const float4*)(ybuf + (size_t)p0 * H_DIM);
    const float4* y1 = (const float4*)(ybuf + (size_t)p1 * H_DIM);
    float4* o = (float4*)(out + (size_t)tk * H_DIM);
#pragma unroll
    for (int i = threadIdx.x; i < H_DIM / 4; i += 256) {
        float4 a = y0[i], b = y1[i];
        float4 r;
        r.x = a.x + b.x; r.y = a.y + b.y; r.z = a.z + b.z; r.w = a.w + b.w;
        o[i] = r;
    }
}

extern "C" void kernel_launch(void* const* d_in, const int* in_sizes, int n_in,
                              void* d_out, int out_size, void* d_ws, size_t ws_size,
                              hipStream_t stream)
{
    const float* x  = (const float*)d_in[0];
    const float* gw = (const float*)d_in[1];
    const float* w1 = (const float*)d_in[2];
    const float* w2 = (const float*)d_in[3];
    const float* w3 = (const float*)d_in[4];
    float* out = (float*)d_out;

    // ---- workspace carve-up ----
    unsigned char* p = (unsigned char*)d_ws;
    int* counts     = (int*)p;  p += 256;
    int* cursors    = (int*)p;  p += 256;
    int* offsets    = (int*)p;  p += 256;
    int* top_e      = (int*)p;  p += 2 * T_TOK * 4;
    float* top_w    = (float*)p; p += 2 * T_TOK * 4;
    int* row_token  = (int*)p;  p += 2 * T_TOK * 4;
    float* row_weight = (float*)p; p += 2 * T_TOK * 4;
    int* inv_pos    = (int*)p;  p += 2 * T_TOK * 4;
    unsigned short* xb = (unsigned short*)p; p += (size_t)T_TOK * H_DIM * 2;
    unsigned short* hb = (unsigned short*)p; p += (size_t)2 * T_TOK * F_DIM * 2;
    float* ybuf = (float*)p;    // 2*T x H fp32

    convert_kernel<<<T_TOK * H_DIM / 2048, 256, 0, stream>>>(x, xb);

    hipMemsetAsync(counts, 0, 64 * sizeof(int), stream);
    gate_kernel<<<T_TOK / 4, 256, 0, stream>>>(x, gw, counts, top_e, top_w);
    scan_kernel<<<1, 64, 0, stream>>>(counts, offsets, cursors);
    scatter_kernel<<<T_TOK / 256, 256, 0, stream>>>(top_e, top_w, offsets, cursors,
                                                    row_token, row_weight, inv_pos);

    dim3 g1(64, F_DIM / 64, NE);    // (64, 20, 12)
    ffn1_kernel<<<g1, 256, 0, stream>>>(xb, w1, w3, counts, offsets, row_token, hb);

    dim3 g2(64, H_DIM / 128, NE);   // (64, 16, 12)
    ffn2_kernel<<<g2, 256, 0, stream>>>(hb, w2, counts, offsets, row_weight, ybuf);

    combine_kernel<<<T_TOK, 256, 0, stream>>>(ybuf, inv_pos, out);
}